// Round 6
// baseline (175.732 us; speedup 1.0000x reference)
//
#include <hip/hip_runtime.h>
#include <hip/hip_bf16.h>

// GraphEncoder: the entire edge/message/update pipeline in the reference is
// dead code (update() output is discarded; h is only ever scaled per-node by
// pooling scores). Live computation:
//   a_n = relu(x_n @ W1 + b1)                       (128-dim, per node)
//   d_{n,k} = a_n . (W2 @ w_k/||w_k||) + b2.(w_k/||w_k||)   k=0..2
//   cascade: s = tanh(c * d_k) on alive nodes, top-k per graph (1024/512/256),
//            c *= s on survivors
//   out_g = ((sum_sel c_n a_n) @ W2 + (sum c_n) b2) / 256
//
// R6: round-0 histogram hoisted into k1 (global per-graph hist, memset-zeroed;
// k2 round 0 starts directly at the scan and recomputes keys on the fly from
// d4 — no LDS staging, no round-0 keygen sweep). Final GEMV parallelized
// across all 16 waves. Selection remains bit-identical to the sort form.

#define NPG    2048
#define NGRAPH 32
#define HP     2112
#define HPAD(b) ((b) + ((b) >> 5))   // pad: bin -> slot, kills bank aliasing

__device__ __forceinline__ unsigned int mono_bits(float z) {
    unsigned int bb = __float_as_uint(z);
    return (bb & 0x80000000u) ? ~bb : (bb | 0x80000000u);
}

__global__ __launch_bounds__(256) void k1_fused(
    const float* __restrict__ x,    // [65536][16]
    const float* __restrict__ W1,   // [16][128]
    const float* __restrict__ b1,   // [128]
    const float* __restrict__ W2,   // [128][128]
    const float* __restrict__ b2,   // [128]
    const float* __restrict__ pw,   // pool_w [3][128]
    float4* __restrict__ d4,        // [65536] {d0,d1,d2,_}
    unsigned int* __restrict__ ghist) // [32][2048] round-0 histogram
{
    __shared__ float4 sW1v[512];                 // W1 as [16][32] float4
    __shared__ float4 sb1v[32];                  // b1
    __shared__ __align__(16) float swn[384];     // normalized pool_w
    __shared__ __align__(16) float sv[384];      // v_k[j] = W2 @ wn_k
    __shared__ float sc[4];                      // c_k = b2 . wn_k
    __shared__ float snorm[3];
    int t = threadIdx.x;
    int lane = t & 63, wv = t >> 6;

    for (int i = t; i < 512; i += 256) sW1v[i] = ((const float4*)W1)[i];
    if (t < 32) sb1v[t] = ((const float4*)b1)[t];
    if (wv < 3) {
        float w0 = pw[wv * 128 + lane];
        float w1 = pw[wv * 128 + 64 + lane];
        float p = w0 * w0 + w1 * w1;
        #pragma unroll
        for (int s = 32; s; s >>= 1) p += __shfl_xor(p, s);
        if (lane == 0) snorm[wv] = sqrtf(p);
    }
    __syncthreads();
    for (int i = t; i < 384; i += 256) swn[i] = pw[i] / snorm[i >> 7];
    __syncthreads();
    // 387 tasks: (k,j) dots of length 128; j==128 -> c_k = b2 . wn_k
    for (int task = t; task < 387; task += 256) {
        int k = task / 129, j = task % 129;
        const float4* r4 = (const float4*)((j < 128) ? (W2 + j * 128) : b2);
        const float* wn = swn + k * 128;
        float p0 = 0.f, p1 = 0.f, p2 = 0.f, p3 = 0.f;
        #pragma unroll 8
        for (int q = 0; q < 32; ++q) {
            float4 w = r4[q];
            p0 = fmaf(w.x, wn[4 * q + 0], p0);
            p1 = fmaf(w.y, wn[4 * q + 1], p1);
            p2 = fmaf(w.z, wn[4 * q + 2], p2);
            p3 = fmaf(w.w, wn[4 * q + 3], p3);
        }
        float p = (p0 + p1) + (p2 + p3);
        if (j < 128) sv[k * 128 + j] = p;
        else sc[k] = p;
    }
    __syncthreads();

    // one node per thread, everything broadcast from LDS
    int n = blockIdx.x * 256 + t;
    const float4* xr = (const float4*)(x + (size_t)n * 16);
    float4 xa = xr[0], xb = xr[1], xc = xr[2], xd = xr[3];
    float xs[16] = {xa.x, xa.y, xa.z, xa.w, xb.x, xb.y, xb.z, xb.w,
                    xc.x, xc.y, xc.z, xc.w, xd.x, xd.y, xd.z, xd.w};
    const float4* sv4 = (const float4*)sv;
    float dd0 = sc[0], dd1 = sc[1], dd2 = sc[2];
    #pragma unroll 4
    for (int fq = 0; fq < 32; ++fq) {
        float4 a4 = sb1v[fq];
        #pragma unroll
        for (int j = 0; j < 16; ++j) {
            float4 w = sW1v[j * 32 + fq];
            a4.x = fmaf(xs[j], w.x, a4.x);
            a4.y = fmaf(xs[j], w.y, a4.y);
            a4.z = fmaf(xs[j], w.z, a4.z);
            a4.w = fmaf(xs[j], w.w, a4.w);
        }
        a4.x = fmaxf(a4.x, 0.f); a4.y = fmaxf(a4.y, 0.f);
        a4.z = fmaxf(a4.z, 0.f); a4.w = fmaxf(a4.w, 0.f);
        float4 v0 = sv4[fq], v1 = sv4[32 + fq], v2 = sv4[64 + fq];
        dd0 = fmaf(a4.x, v0.x, fmaf(a4.y, v0.y, fmaf(a4.z, v0.z, fmaf(a4.w, v0.w, dd0))));
        dd1 = fmaf(a4.x, v1.x, fmaf(a4.y, v1.y, fmaf(a4.z, v1.z, fmaf(a4.w, v1.w, dd1))));
        dd2 = fmaf(a4.x, v2.x, fmaf(a4.y, v2.y, fmaf(a4.z, v2.z, fmaf(a4.w, v2.w, dd2))));
    }
    d4[n] = make_float4(dd0, dd1, dd2, 0.f);
    // round-0 histogram contribution: bin = top bits of mono(d0)
    atomicAdd(&ghist[(n >> 11) * 2048 + (mono_bits(dd0) >> 22)], 1u);
}

// one block per graph: round-0 select straight off the precomputed global
// hist (keys recomputed on the fly), rounds 1-2 via fused LDS keygen/hist +
// early-exit radix + ballot compaction, then the gather-GEMV epilogue.
__global__ __launch_bounds__(1024, 1) void k2_cascade(
    const float* __restrict__ x,
    const float* __restrict__ W1,
    const float* __restrict__ b1,
    const float* __restrict__ W2,
    const float* __restrict__ b2,
    const float4* __restrict__ d4,
    const unsigned int* __restrict__ ghist,
    float* __restrict__ out)        // [32][128]
{
    __shared__ unsigned long long sKey[1024];
    __shared__ unsigned int hist[2][HP];
    __shared__ int   idxB[1024];
    __shared__ float cscB[1024], d1B[1024], d2B[1024];
    __shared__ int   idxA2[512];
    __shared__ float cscA2[512], d2A2[512];
    __shared__ float sW1[2048], sb1[128];
    __shared__ float Spart[1024], Svec[128], red4[4];
    __shared__ unsigned long long sPrefix;
    __shared__ int sNeed, sDone, sCnt;

    int t = threadIdx.x, g = blockIdx.x;
    int lane = t & 63, wv = t >> 6;
    const float4* d4g = d4 + (size_t)g * NPG;

    for (int i = t; i < 2048; i += 1024) sW1[i] = W1[i];
    if (t < 128) sb1[t] = b1[t];
    for (int i = t; i < 2 * HP; i += 1024) ((unsigned int*)hist)[i] = 0u;
    if (t == 0) { sPrefix = 0ull; sNeed = 1024; sDone = 0; sCnt = 0; }
    __syncthreads();

    // ---------------- round 0 (N=2048, k=1024), hist precomputed ----------
    // key = mono(d0)<<11 | (2047-n): desc == (score desc, idx asc), exactly
    // lax.top_k order; tanh monotone -> rank by z directly.
    if (wv == 0) {   // pass-0 scan of global hist; lane L owns bins [32L,32L+32)
        const uint4* gh = (const uint4*)(ghist + (size_t)g * 2048 + 32 * t);
        unsigned int h[32], tl = 0;
        #pragma unroll
        for (int i = 0; i < 8; ++i) {
            uint4 q = gh[i];
            h[4 * i + 0] = q.x; h[4 * i + 1] = q.y;
            h[4 * i + 2] = q.z; h[4 * i + 3] = q.w;
            tl += q.x + q.y + q.z + q.w;
        }
        unsigned int need = 1024u;
        unsigned int s = tl;   // inclusive suffix-sum across lanes
        #pragma unroll
        for (int d = 1; d < 64; d <<= 1) {
            unsigned int v = __shfl_down(s, d);
            if (t + d < 64) s += v;
        }
        unsigned int above = s - tl;
        if (above < need && above + tl >= need) {   // unique owner lane
            unsigned int cum = above;
            #pragma unroll
            for (int b = 31; b >= 0; --b) {
                cum += h[b];
                if (cum >= need) {
                    int nn = (int)(need - (cum - h[b]));
                    sNeed = nn;
                    sPrefix = (unsigned long long)(unsigned int)(32 * t + b) << 33;
                    sDone = (nn == (int)h[b]);
                    break;
                }
            }
        }
    }
    __syncthreads();
    int lastBuf = -1;
    for (int pass = 1; pass < 4 && !sDone; ++pass) {
        int buf = pass & 1;
        int shift = 33 - 11 * pass;
        lastBuf = buf;
        unsigned long long pref = sPrefix;
        for (int m = t; m < NPG; m += 1024) {   // keys recomputed on the fly
            unsigned long long kv =
                ((unsigned long long)mono_bits(d4g[m].x) << 11)
                | (unsigned long long)(unsigned int)(2047 - m);
            if ((kv >> (shift + 11)) == (pref >> (shift + 11)))
                atomicAdd(&hist[buf][HPAD((unsigned int)(kv >> shift) & 2047u)], 1u);
        }
        __syncthreads();
        if (wv == 0) {
            unsigned int need = (unsigned int)sNeed;
            unsigned int h[32], tl = 0;
            #pragma unroll
            for (int b = 0; b < 32; ++b) {
                h[b] = hist[buf][HPAD(32u * t + b)];
                tl += h[b];
            }
            unsigned int s = tl;
            #pragma unroll
            for (int d = 1; d < 64; d <<= 1) {
                unsigned int v = __shfl_down(s, d);
                if (t + d < 64) s += v;
            }
            unsigned int above = s - tl;
            if (above < need && above + tl >= need) {
                unsigned int cum = above;
                #pragma unroll
                for (int b = 31; b >= 0; --b) {
                    cum += h[b];
                    if (cum >= need) {
                        int nn = (int)(need - (cum - h[b]));
                        sNeed = nn;
                        sPrefix = pref |
                            ((unsigned long long)(unsigned int)(32 * t + b) << shift);
                        sDone = (nn == (int)h[b]) || (pass == 3);
                        break;
                    }
                }
            }
        } else if (pass >= 2) {
            for (int i = t - 64; i < HP; i += 960) hist[buf ^ 1][i] = 0u;
        }
        __syncthreads();
    }
    {   // round-0 compaction
        unsigned long long thr = sPrefix;
        if (lastBuf >= 0)
            for (int i = t; i < HP; i += 1024) hist[lastBuf][i] = 0u;
        for (int m = t; m < NPG; m += 1024) {
            float4 dd = d4g[m];
            unsigned long long kv =
                ((unsigned long long)mono_bits(dd.x) << 11)
                | (unsigned long long)(unsigned int)(2047 - m);
            bool pred = (kv >= thr);   // keys distinct -> exactly 1024 selected
            unsigned long long mask = __ballot(pred);
            if (mask) {
                int leader = __ffsll((long long)mask) - 1;
                int cnt = __popcll(mask);
                int base = 0;
                if (lane == leader) base = atomicAdd(&sCnt, cnt);
                base = __shfl(base, leader);
                if (pred) {
                    int rank = __popcll(mask & ((1ull << lane) - 1ull));
                    int pos = base + rank;
                    idxB[pos] = m;
                    cscB[pos] = tanhf(dd.x);
                    d1B[pos] = dd.y;
                    d2B[pos] = dd.z;
                }
            }
        }
        __syncthreads();
    }

    // ---------------- rounds 1,2 (LDS keygen fused with pass-0 hist) ------
    int curN = 1024;
    for (int r = 1; r < 3; ++r) {
        int kk = 1024 >> r;
        const float* dIn   = (r == 1) ? d1B : d2A2;
        const float* cscIn = (r == 1) ? cscB : cscA2;
        const int*   idxIn = (r == 1) ? idxB : idxA2;
        int*   idxOut = (r == 1) ? idxA2 : idxB;
        float* cscOut = (r == 1) ? cscA2 : cscB;

        if (t == 0) { sPrefix = 0ull; sNeed = kk; sDone = 0; sCnt = 0; }
        for (int m = t; m < curN; m += 1024) {
            float z = cscIn[m] * dIn[m];
            unsigned long long kv = ((unsigned long long)mono_bits(z) << 11)
                | (unsigned long long)(unsigned int)(2047 - idxIn[m]);
            sKey[m] = kv;
            atomicAdd(&hist[0][HPAD((unsigned int)(kv >> 33) & 2047u)], 1u);
        }
        __syncthreads();

        lastBuf = 0;
        for (int pass = 0; pass < 4; ++pass) {
            int buf = pass & 1;
            int shift = 33 - 11 * pass;
            lastBuf = buf;
            if (pass > 0) {
                unsigned long long pref = sPrefix;
                for (int m = t; m < curN; m += 1024) {
                    unsigned long long kv = sKey[m];
                    if ((kv >> (shift + 11)) == (pref >> (shift + 11)))
                        atomicAdd(&hist[buf][HPAD((unsigned int)(kv >> shift) & 2047u)], 1u);
                }
                __syncthreads();
            }
            if (wv == 0) {
                unsigned long long pref = sPrefix;
                unsigned int need = (unsigned int)sNeed;
                unsigned int h[32], tl = 0;
                #pragma unroll
                for (int b = 0; b < 32; ++b) {
                    h[b] = hist[buf][HPAD(32u * t + b)];
                    tl += h[b];
                }
                unsigned int s = tl;
                #pragma unroll
                for (int d = 1; d < 64; d <<= 1) {
                    unsigned int v = __shfl_down(s, d);
                    if (t + d < 64) s += v;
                }
                unsigned int above = s - tl;
                if (above < need && above + tl >= need) {
                    unsigned int cum = above;
                    #pragma unroll
                    for (int b = 31; b >= 0; --b) {
                        cum += h[b];
                        if (cum >= need) {
                            int nn = (int)(need - (cum - h[b]));
                            sNeed = nn;
                            sPrefix = pref |
                                ((unsigned long long)(unsigned int)(32 * t + b) << shift);
                            sDone = (nn == (int)h[b]) || (pass == 3);
                            break;
                        }
                    }
                }
            } else if (pass > 0) {
                for (int i = t - 64; i < HP; i += 960) hist[buf ^ 1][i] = 0u;
            }
            __syncthreads();
            if (sDone) break;
        }
        unsigned long long thr = sPrefix;

        for (int i = t; i < HP; i += 1024) hist[lastBuf][i] = 0u;
        for (int m = t; m < curN; m += 1024) {
            unsigned long long kv = sKey[m];
            bool pred = (kv >= thr);
            unsigned long long mask = __ballot(pred);
            if (mask) {
                int leader = __ffsll((long long)mask) - 1;
                int cnt = __popcll(mask);
                int base = 0;
                if (lane == leader) base = atomicAdd(&sCnt, cnt);
                base = __shfl(base, leader);
                if (pred) {
                    int rank = __popcll(mask & ((1ull << lane) - 1ull));
                    int pos = base + rank;
                    float ci = cscIn[m];
                    idxOut[pos] = idxIn[m];
                    cscOut[pos] = ci * tanhf(ci * dIn[m]);
                    if (r == 1) d2A2[pos] = d2B[m];
                }
            }
        }
        __syncthreads();
        curN = kk;
    }

    // ---------------- epilogue ----------------
    // S[f] = sum_{sel} c_n * relu(x_n @ W1 + b1)[f]; sel/csc in idxB/cscB[0..256)
    {
        int f = t & 127, grp = t >> 7;
        float Sacc = 0.f;
        #pragma unroll 2
        for (int it = grp; it < 256; it += 8) {
            int n = idxB[it];
            float cn = cscB[it];
            const float4* xr = (const float4*)(x + (size_t)(g * NPG + n) * 16);
            float4 xa = xr[0], xb = xr[1], xc = xr[2], xd = xr[3];
            float acc = sb1[f];
            acc = fmaf(xa.x, sW1[0 * 128 + f], acc);
            acc = fmaf(xa.y, sW1[1 * 128 + f], acc);
            acc = fmaf(xa.z, sW1[2 * 128 + f], acc);
            acc = fmaf(xa.w, sW1[3 * 128 + f], acc);
            acc = fmaf(xb.x, sW1[4 * 128 + f], acc);
            acc = fmaf(xb.y, sW1[5 * 128 + f], acc);
            acc = fmaf(xb.z, sW1[6 * 128 + f], acc);
            acc = fmaf(xb.w, sW1[7 * 128 + f], acc);
            acc = fmaf(xc.x, sW1[8 * 128 + f], acc);
            acc = fmaf(xc.y, sW1[9 * 128 + f], acc);
            acc = fmaf(xc.z, sW1[10 * 128 + f], acc);
            acc = fmaf(xc.w, sW1[11 * 128 + f], acc);
            acc = fmaf(xd.x, sW1[12 * 128 + f], acc);
            acc = fmaf(xd.y, sW1[13 * 128 + f], acc);
            acc = fmaf(xd.z, sW1[14 * 128 + f], acc);
            acc = fmaf(xd.w, sW1[15 * 128 + f], acc);
            Sacc += fmaxf(acc, 0.f) * cn;
        }
        Spart[t] = Sacc;
    }
    if (t < 256) {   // Csum = sum_{sel} c_n
        float cpart = cscB[t];
        #pragma unroll
        for (int s = 32; s; s >>= 1) cpart += __shfl_xor(cpart, s);
        if ((t & 63) == 0) red4[t >> 6] = cpart;
    }
    __syncthreads();
    if (t < 128) {
        float sv = 0.f;
        #pragma unroll
        for (int h = 0; h < 8; ++h) sv += Spart[h * 128 + t];
        Svec[t] = sv;
    }
    __syncthreads();
    {   // GEMV: all 16 waves; group jc handles j in [16*jc, 16*jc+16)
        int f = t & 127, jc = t >> 7;
        float part = 0.f;
        #pragma unroll
        for (int j = 16 * jc; j < 16 * jc + 16; ++j)
            part = fmaf(Svec[j], W2[j * 128 + f], part);
        Spart[t] = part;
    }
    __syncthreads();
    if (t < 128) {
        float Csum = (red4[0] + red4[1]) + (red4[2] + red4[3]);
        float acc = Csum * b2[t];
        #pragma unroll
        for (int h = 0; h < 8; ++h) acc += Spart[h * 128 + t];
        out[g * 128 + t] = acc * (1.0f / 256.0f);
    }
}

extern "C" void kernel_launch(void* const* d_in, const int* in_sizes, int n_in,
                              void* d_out, int out_size, void* d_ws, size_t ws_size,
                              hipStream_t stream) {
    const float* x  = (const float*)d_in[0];
    const float* W1 = (const float*)d_in[2];   // node_w1 [16][128]
    const float* b1 = (const float*)d_in[3];   // node_b1 [128]
    const float* W2 = (const float*)d_in[4];   // node_w2 [128][128]
    const float* b2 = (const float*)d_in[5];   // node_b2 [128]
    const float* pw = (const float*)d_in[22];  // pool_w  [3][128]
    float* out = (float*)d_out;

    float4* d4 = (float4*)d_ws;                                   // 1 MB
    unsigned int* ghist = (unsigned int*)((char*)d_ws + (1 << 20)); // 256 KB

    hipMemsetAsync(ghist, 0, NGRAPH * 2048 * sizeof(unsigned int), stream);
    k1_fused<<<256, 256, 0, stream>>>(x, W1, b1, W2, b2, pw, d4, ghist);
    k2_cascade<<<NGRAPH, 1024, 0, stream>>>(x, W1, b1, W2, b2, d4, ghist, out);
}

// Round 7
// 175.578 us; speedup vs baseline: 1.0009x; 1.0009x over previous
//
#include <hip/hip_runtime.h>
#include <hip/hip_bf16.h>

// GraphEncoder: the entire edge/message/update pipeline in the reference is
// dead code (update() output is discarded; h is only ever scaled per-node by
// pooling scores). Live computation:
//   a_n = relu(x_n @ W1 + b1)                       (128-dim, per node)
//   d_{n,k} = a_n . (W2 @ w_k/||w_k||) + b2.(w_k/||w_k||)   k=0..2
//   cascade: s = tanh(c * d_k) on alive nodes, top-k per graph (1024/512/256),
//            c *= s on survivors
//   out_g = ((sum_sel c_n a_n) @ W2 + (sum c_n) b2) / 256
//
// R7: revert R6's global-hist hoist (regressed). Keep 16-wave GEMV epilogue.
// New: (a) k1 reads W1/b1 via wave-uniform GLOBAL loads (scalar pipe) instead
// of 640 broadcast ds_read_b128/thread — k1 was LDS-throughput-bound;
// (b) k2 fuses d4 load + keygen + hist0 into one sweep (loads issued before
// the hist-zero barrier), d0A eliminated (z decoded exactly from key bits).
// Selection remains bit-identical to the sort formulation.

#define NPG    2048
#define NGRAPH 32
#define HP     2112
#define HPAD(b) ((b) + ((b) >> 5))   // pad: bin -> slot, kills bank aliasing

__device__ __forceinline__ unsigned int mono_bits(float z) {
    unsigned int bb = __float_as_uint(z);
    return (bb & 0x80000000u) ? ~bb : (bb | 0x80000000u);
}
__device__ __forceinline__ float mono_decode(unsigned int mo) {
    unsigned int bb = (mo & 0x80000000u) ? (mo & 0x7FFFFFFFu) : ~mo;
    return __uint_as_float(bb);
}

__global__ __launch_bounds__(256) void k1_fused(
    const float* __restrict__ x,    // [65536][16]
    const float* __restrict__ W1,   // [16][128]
    const float* __restrict__ b1,   // [128]
    const float* __restrict__ W2,   // [128][128]
    const float* __restrict__ b2,   // [128]
    const float* __restrict__ pw,   // pool_w [3][128]
    float4* __restrict__ d4)        // [65536] {d0,d1,d2,_}
{
    __shared__ __align__(16) float swn[384];     // normalized pool_w
    __shared__ __align__(16) float sv[384];      // v_k[j] = W2 @ wn_k
    __shared__ float sc[4];                      // c_k = b2 . wn_k
    __shared__ float snorm[3];
    int t = threadIdx.x;
    int lane = t & 63, wv = t >> 6;

    if (wv < 3) {
        float w0 = pw[wv * 128 + lane];
        float w1 = pw[wv * 128 + 64 + lane];
        float p = w0 * w0 + w1 * w1;
        #pragma unroll
        for (int s = 32; s; s >>= 1) p += __shfl_xor(p, s);
        if (lane == 0) snorm[wv] = sqrtf(p);
    }
    __syncthreads();
    for (int i = t; i < 384; i += 256) swn[i] = pw[i] / snorm[i >> 7];
    __syncthreads();
    // 387 tasks: (k,j) dots of length 128; j==128 -> c_k = b2 . wn_k
    for (int task = t; task < 387; task += 256) {
        int k = task / 129, j = task % 129;
        const float4* r4 = (const float4*)((j < 128) ? (W2 + j * 128) : b2);
        const float* wn = swn + k * 128;
        float p0 = 0.f, p1 = 0.f, p2 = 0.f, p3 = 0.f;
        #pragma unroll 8
        for (int q = 0; q < 32; ++q) {
            float4 w = r4[q];
            p0 = fmaf(w.x, wn[4 * q + 0], p0);
            p1 = fmaf(w.y, wn[4 * q + 1], p1);
            p2 = fmaf(w.z, wn[4 * q + 2], p2);
            p3 = fmaf(w.w, wn[4 * q + 3], p3);
        }
        float p = (p0 + p1) + (p2 + p3);
        if (j < 128) sv[k * 128 + j] = p;
        else sc[k] = p;
    }
    __syncthreads();

    // one node per thread; W1/b1 via wave-uniform global loads (scalar pipe),
    // only the block-computed v comes from LDS (broadcast, 96 reads/thread)
    const float4* W1v = (const float4*)W1;
    const float4* b1v = (const float4*)b1;
    int n = blockIdx.x * 256 + t;
    const float4* xr = (const float4*)(x + (size_t)n * 16);
    float4 xa = xr[0], xb = xr[1], xc = xr[2], xd = xr[3];
    float xs[16] = {xa.x, xa.y, xa.z, xa.w, xb.x, xb.y, xb.z, xb.w,
                    xc.x, xc.y, xc.z, xc.w, xd.x, xd.y, xd.z, xd.w};
    const float4* sv4 = (const float4*)sv;
    float dd0 = sc[0], dd1 = sc[1], dd2 = sc[2];
    #pragma unroll 4
    for (int fq = 0; fq < 32; ++fq) {
        float4 a4 = b1v[fq];
        #pragma unroll
        for (int j = 0; j < 16; ++j) {
            float4 w = W1v[j * 32 + fq];
            a4.x = fmaf(xs[j], w.x, a4.x);
            a4.y = fmaf(xs[j], w.y, a4.y);
            a4.z = fmaf(xs[j], w.z, a4.z);
            a4.w = fmaf(xs[j], w.w, a4.w);
        }
        a4.x = fmaxf(a4.x, 0.f); a4.y = fmaxf(a4.y, 0.f);
        a4.z = fmaxf(a4.z, 0.f); a4.w = fmaxf(a4.w, 0.f);
        float4 v0 = sv4[fq], v1 = sv4[32 + fq], v2 = sv4[64 + fq];
        dd0 = fmaf(a4.x, v0.x, fmaf(a4.y, v0.y, fmaf(a4.z, v0.z, fmaf(a4.w, v0.w, dd0))));
        dd1 = fmaf(a4.x, v1.x, fmaf(a4.y, v1.y, fmaf(a4.z, v1.z, fmaf(a4.w, v1.w, dd1))));
        dd2 = fmaf(a4.x, v2.x, fmaf(a4.y, v2.y, fmaf(a4.z, v2.z, fmaf(a4.w, v2.w, dd2))));
    }
    d4[n] = make_float4(dd0, dd1, dd2, 0.f);
}

// one block per graph: 3x (fused keygen/hist0 + early-exit radix + ballot
// compaction) + gather-GEMV epilogue. z decoded from key bits (exact).
__global__ __launch_bounds__(1024, 1) void k2_cascade(
    const float* __restrict__ x,
    const float* __restrict__ W1,
    const float* __restrict__ b1,
    const float* __restrict__ W2,
    const float* __restrict__ b2,
    const float4* __restrict__ d4,
    float* __restrict__ out)        // [32][128]
{
    __shared__ unsigned long long sKey[NPG];
    __shared__ float d1A[NPG], d2A[NPG];
    __shared__ unsigned int hist[2][HP];
    __shared__ int   idxB[1024];
    __shared__ float cscB[1024], d1B[1024], d2B[1024];
    __shared__ int   idxA2[512];
    __shared__ float cscA2[512], d2A2[512];
    __shared__ float sW1[2048], sb1[128];
    __shared__ float Spart[1024], Svec[128], red4[4];
    __shared__ unsigned long long sPrefix;
    __shared__ int sNeed, sDone, sCnt;

    int t = threadIdx.x, g = blockIdx.x;
    int lane = t & 63, wv = t >> 6;
    const float4* d4g = d4 + (size_t)g * NPG;

    // issue the d-loads FIRST so HBM latency hides under the zero/stage phase
    float4 e0 = d4g[t];
    float4 e1 = d4g[t + 1024];
    for (int i = t; i < 2048; i += 1024) sW1[i] = W1[i];
    if (t < 128) sb1[t] = b1[t];
    for (int i = t; i < 2 * HP; i += 1024) ((unsigned int*)hist)[i] = 0u;
    if (t == 0) { sPrefix = 0ull; sNeed = 1024; sDone = 0; sCnt = 0; }
    __syncthreads();

    // fused: stage d1/d2 + round-0 keygen + pass-0 histogram.
    // key = mono(z)<<11 | (2047-n): desc == (score desc, idx asc), exactly
    // lax.top_k order; tanh monotone -> rank by z = c*d directly.
    {
        unsigned long long kv0 = ((unsigned long long)mono_bits(e0.x) << 11)
                               | (unsigned long long)(unsigned int)(2047 - t);
        d1A[t] = e0.y; d2A[t] = e0.z;
        sKey[t] = kv0;
        atomicAdd(&hist[0][HPAD((unsigned int)(kv0 >> 33) & 2047u)], 1u);
        int n1 = t + 1024;
        unsigned long long kv1 = ((unsigned long long)mono_bits(e1.x) << 11)
                               | (unsigned long long)(unsigned int)(2047 - n1);
        d1A[n1] = e1.y; d2A[n1] = e1.z;
        sKey[n1] = kv1;
        atomicAdd(&hist[0][HPAD((unsigned int)(kv1 >> 33) & 2047u)], 1u);
    }
    __syncthreads();

    int curN = NPG;
    for (int r = 0; r < 3; ++r) {
        int kk = 1024 >> r;
        const float* cscIn = (r == 1) ? cscB : cscA2;   // unused for r==0
        int*   idxOut = (r == 1) ? idxA2 : idxB;
        float* cscOut = (r == 1) ? cscA2 : cscB;

        if (r > 0) {   // keygen + pass-0 hist for rounds 1,2 (round 0 done)
            const float* dIn   = (r == 1) ? d1B : d2A2;
            const int*   idxIn = (r == 1) ? idxB : idxA2;
            if (t == 0) { sPrefix = 0ull; sNeed = kk; sDone = 0; sCnt = 0; }
            __syncthreads();
            for (int m = t; m < curN; m += 1024) {
                float z = cscIn[m] * dIn[m];
                unsigned long long kv = ((unsigned long long)mono_bits(z) << 11)
                    | (unsigned long long)(unsigned int)(2047 - idxIn[m]);
                sKey[m] = kv;
                atomicAdd(&hist[0][HPAD((unsigned int)(kv >> 33) & 2047u)], 1u);
            }
            __syncthreads();
        }

        int lastBuf = 0;
        for (int pass = 0; pass < 4; ++pass) {
            int buf = pass & 1;
            int shift = 33 - 11 * pass;
            lastBuf = buf;
            if (pass > 0) {  // histogram candidates under current prefix
                unsigned long long pref = sPrefix;
                for (int m = t; m < curN; m += 1024) {
                    unsigned long long kv = sKey[m];
                    if ((kv >> (shift + 11)) == (pref >> (shift + 11)))
                        atomicAdd(&hist[buf][HPAD((unsigned int)(kv >> shift) & 2047u)], 1u);
                }
                __syncthreads();
            }
            if (wv == 0) {   // wave 0: scan 2048 bins, lane L owns [32L,32L+32)
                unsigned long long pref = sPrefix;
                unsigned int need = (unsigned int)sNeed;
                unsigned int h[32], tl = 0;
                #pragma unroll
                for (int b = 0; b < 32; ++b) {
                    h[b] = hist[buf][HPAD(32u * t + b)];
                    tl += h[b];
                }
                unsigned int s = tl;   // inclusive suffix-sum across lanes
                #pragma unroll
                for (int d = 1; d < 64; d <<= 1) {
                    unsigned int v = __shfl_down(s, d);
                    if (t + d < 64) s += v;
                }
                unsigned int above = s - tl;   // sum over lanes > L
                if (above < need && above + tl >= need) {   // unique owner
                    unsigned int cum = above;
                    #pragma unroll
                    for (int b = 31; b >= 0; --b) {
                        cum += h[b];
                        if (cum >= need) {
                            int nn = (int)(need - (cum - h[b]));
                            sNeed = nn;
                            sPrefix = pref |
                                ((unsigned long long)(unsigned int)(32 * t + b) << shift);
                            // early exit: whole boundary bucket selected ->
                            // thr = prefix (low bits 0) picks exactly kk keys
                            sDone = (nn == (int)h[b]) || (pass == 3);
                            break;
                        }
                    }
                }
            } else if (pass > 0) {
                // waves 1..15: zero the other buffer (used by previous pass,
                // needed zero by the next one) while wave 0 scans
                for (int i = t - 64; i < HP; i += 960) hist[buf ^ 1][i] = 0u;
            }
            __syncthreads();
            if (sDone) break;
        }
        unsigned long long thr = sPrefix;

        // compaction (ballot-aggregated: one LDS atomic per wave-iteration)
        // + zero the one still-dirty hist buffer for the next round
        for (int i = t; i < HP; i += 1024) hist[lastBuf][i] = 0u;
        for (int m = t; m < curN; m += 1024) {
            unsigned long long kv = sKey[m];
            bool pred = (kv >= thr);   // keys distinct -> exactly kk selected
            unsigned long long mask = __ballot(pred);
            if (mask) {
                int leader = __ffsll((long long)mask) - 1;
                int cnt = __popcll(mask);
                int base = 0;
                if (lane == leader) base = atomicAdd(&sCnt, cnt);
                base = __shfl(base, leader);
                if (pred) {
                    int rank = __popcll(mask & ((1ull << lane) - 1ull));
                    int pos = base + rank;
                    float z = mono_decode((unsigned int)(kv >> 11)); // exact z
                    int ni = 2047 - (int)((unsigned int)kv & 2047u);
                    idxOut[pos] = ni;
                    if (r == 0) {
                        cscOut[pos] = tanhf(z);
                        d1B[pos] = d1A[m]; d2B[pos] = d2A[m];
                    } else {
                        cscOut[pos] = cscIn[m] * tanhf(z);
                        if (r == 1) d2A2[pos] = d2B[m];
                    }
                }
            }
        }
        __syncthreads();
        curN = kk;
    }

    // ---------------- epilogue ----------------
    // S[f] = sum_{sel} c_n * relu(x_n @ W1 + b1)[f]; sel/csc in idxB/cscB[0..256)
    {
        int f = t & 127, grp = t >> 7;
        float Sacc = 0.f;
        #pragma unroll 2
        for (int it = grp; it < 256; it += 8) {
            int n = idxB[it];
            float cn = cscB[it];
            const float4* xr = (const float4*)(x + (size_t)(g * NPG + n) * 16);
            float4 xa = xr[0], xb = xr[1], xc = xr[2], xd = xr[3];
            float acc = sb1[f];
            acc = fmaf(xa.x, sW1[0 * 128 + f], acc);
            acc = fmaf(xa.y, sW1[1 * 128 + f], acc);
            acc = fmaf(xa.z, sW1[2 * 128 + f], acc);
            acc = fmaf(xa.w, sW1[3 * 128 + f], acc);
            acc = fmaf(xb.x, sW1[4 * 128 + f], acc);
            acc = fmaf(xb.y, sW1[5 * 128 + f], acc);
            acc = fmaf(xb.z, sW1[6 * 128 + f], acc);
            acc = fmaf(xb.w, sW1[7 * 128 + f], acc);
            acc = fmaf(xc.x, sW1[8 * 128 + f], acc);
            acc = fmaf(xc.y, sW1[9 * 128 + f], acc);
            acc = fmaf(xc.z, sW1[10 * 128 + f], acc);
            acc = fmaf(xc.w, sW1[11 * 128 + f], acc);
            acc = fmaf(xd.x, sW1[12 * 128 + f], acc);
            acc = fmaf(xd.y, sW1[13 * 128 + f], acc);
            acc = fmaf(xd.z, sW1[14 * 128 + f], acc);
            acc = fmaf(xd.w, sW1[15 * 128 + f], acc);
            Sacc += fmaxf(acc, 0.f) * cn;
        }
        Spart[t] = Sacc;
    }
    if (t < 256) {   // Csum = sum_{sel} c_n
        float cpart = cscB[t];
        #pragma unroll
        for (int s = 32; s; s >>= 1) cpart += __shfl_xor(cpart, s);
        if ((t & 63) == 0) red4[t >> 6] = cpart;
    }
    __syncthreads();
    if (t < 128) {
        float sv = 0.f;
        #pragma unroll
        for (int h = 0; h < 8; ++h) sv += Spart[h * 128 + t];
        Svec[t] = sv;
    }
    __syncthreads();
    {   // GEMV: all 16 waves; group jc handles j in [16*jc, 16*jc+16)
        int f = t & 127, jc = t >> 7;
        float part = 0.f;
        #pragma unroll
        for (int j = 16 * jc; j < 16 * jc + 16; ++j)
            part = fmaf(Svec[j], W2[j * 128 + f], part);
        Spart[t] = part;
    }
    __syncthreads();
    if (t < 128) {
        float Csum = (red4[0] + red4[1]) + (red4[2] + red4[3]);
        float acc = Csum * b2[t];
        #pragma unroll
        for (int h = 0; h < 8; ++h) acc += Spart[h * 128 + t];
        out[g * 128 + t] = acc * (1.0f / 256.0f);
    }
}

extern "C" void kernel_launch(void* const* d_in, const int* in_sizes, int n_in,
                              void* d_out, int out_size, void* d_ws, size_t ws_size,
                              hipStream_t stream) {
    const float* x  = (const float*)d_in[0];
    const float* W1 = (const float*)d_in[2];   // node_w1 [16][128]
    const float* b1 = (const float*)d_in[3];   // node_b1 [128]
    const float* W2 = (const float*)d_in[4];   // node_w2 [128][128]
    const float* b2 = (const float*)d_in[5];   // node_b2 [128]
    const float* pw = (const float*)d_in[22];  // pool_w  [3][128]
    float* out = (float*)d_out;

    float4* d4 = (float4*)d_ws;   // [65536] float4 = 1 MB

    k1_fused<<<256, 256, 0, stream>>>(x, W1, b1, W2, b2, pw, d4);
    k2_cascade<<<NGRAPH, 1024, 0, stream>>>(x, W1, b1, W2, b2, d4, out);
}